// Round 3
// baseline (110.259 us; speedup 1.0000x reference)
//
#include <hip/hip_runtime.h>
#include <math.h>
#include <limits.h>

// out[b,h,w,c] = vgg[b,h,w,c] - t[b,h,w]
//   t = (a > 0.5f) ? a : 0,  a[b,h,w] = interm[b,h,w, argmax_c logits[b,c]]
// B=256, H=W=7 (P=49 positions), C_in=1000, C_out=512. All fp32.
//
// Two kernels:
//   A) one block per sample: argmax(logits[b,:]) -> gather 49 CAM values ->
//      threshold -> write 49 floats to d_ws.   (tiny: ~1 MB read)
//   B) pure grid-stride float4 stream: out = vgg - ws[pos]. No barriers,
//      no LDS, nontemporal loads/stores (no reuse).  51.4 MB -> ~10 us.

#define NB     256      // batch
#define NP     49       // 7*7 positions
#define CIN    1000     // interm / logits channels
#define COUT   512      // vgg channels
#define N4     (NB * NP * COUT / 4)   // 1,605,632 float4 total

typedef float vf4 __attribute__((ext_vector_type(4)));  // clang-native for nontemporal builtins

__global__ __launch_bounds__(256) void cam_kernel(
    const float* __restrict__ interm,
    const float* __restrict__ logits,
    float* __restrict__ ws)
{
    const int b   = blockIdx.x;
    const int tid = threadIdx.x;

    // ---- per-sample argmax over logits[b, 0..999] ----
    const float* lg = logits + b * CIN;
    float bv = -INFINITY;
    int   bi = INT_MAX;
    for (int i = tid; i < CIN; i += 256) {
        float v = lg[i];
        if (v > bv || (v == bv && i < bi)) { bv = v; bi = i; }
    }
    for (int off = 32; off >= 1; off >>= 1) {
        float ov = __shfl_down(bv, off, 64);
        int   oi = __shfl_down(bi, off, 64);
        if (ov > bv || (ov == bv && oi < bi)) { bv = ov; bi = oi; }
    }
    __shared__ float wv[4];
    __shared__ int   wi[4];
    __shared__ int   s_idx;
    const int wave = tid >> 6;
    if ((tid & 63) == 0) { wv[wave] = bv; wi[wave] = bi; }
    __syncthreads();
    if (tid == 0) {
        float v = wv[0]; int i = wi[0];
        #pragma unroll
        for (int w = 1; w < 4; ++w)
            if (wv[w] > v || (wv[w] == v && wi[w] < i)) { v = wv[w]; i = wi[w]; }
        s_idx = i;
    }
    __syncthreads();
    const int idx = s_idx;

    // ---- gather + threshold the 49 CAM values -> workspace ----
    if (tid < NP) {
        float a = interm[((size_t)b * NP + tid) * CIN + idx];
        ws[b * NP + tid] = (a > 0.5f) ? a : 0.0f;
    }
}

__global__ __launch_bounds__(256) void sub_kernel(
    const float* __restrict__ vgg,
    const float* __restrict__ ws,
    float* __restrict__ out)
{
    const vf4* __restrict__ vgg4 = (const vf4*)vgg;
    vf4*       __restrict__ out4 = (vf4*)out;
    const int stride = gridDim.x * 256;
    for (int v = blockIdx.x * 256 + threadIdx.x; v < N4; v += stride) {
        const float a = ws[v >> 7];            // 128 float4 per (b,h,w) position
        vf4 x = __builtin_nontemporal_load(&vgg4[v]);
        x -= a;
        __builtin_nontemporal_store(x, &out4[v]);
    }
}

extern "C" void kernel_launch(void* const* d_in, const int* in_sizes, int n_in,
                              void* d_out, int out_size, void* d_ws, size_t ws_size,
                              hipStream_t stream) {
    const float* vgg    = (const float*)d_in[0];  // [256,7,7,512]
    const float* interm = (const float*)d_in[1];  // [256,7,7,1000]
    const float* logits = (const float*)d_in[2];  // [256,1000]
    float* out = (float*)d_out;                   // [256,7,7,512]
    float* ws  = (float*)d_ws;                    // >= 256*49 floats

    hipLaunchKernelGGL(cam_kernel, dim3(NB), dim3(256), 0, stream,
                       interm, logits, ws);
    hipLaunchKernelGGL(sub_kernel, dim3(2048), dim3(256), 0, stream,
                       vgg, ws, out);
}